// Round 1
// baseline (89.344 us; speedup 1.0000x reference)
//
#include <hip/hip_runtime.h>
#include <math.h>

#define RES 32
#define GRID_G (RES * RES * RES)   // 32768
#define NPTS 256
#define NB 32                      // n-chunk per block
#define BLK 256

__global__ __launch_bounds__(BLK) void gauss_splat_kernel(
    const float* __restrict__ points,     // [N,3]
    const float* __restrict__ positions,  // [G,3]
    const float* __restrict__ scales,     // [G,3]
    const float* __restrict__ rotations,  // [G,4]
    const float* __restrict__ opacity,    // [G]
    const float* __restrict__ sh,         // [G,9]
    float* __restrict__ out_rgb,          // [N,G]
    float* __restrict__ out_sigma)        // [G]
{
    const int g  = blockIdx.x * BLK + threadIdx.x;   // one gaussian per thread
    const int n0 = blockIdx.y * NB;                  // n-chunk base

    // Stage this block's point chunk in LDS (pre-scaled by 1/4).
    __shared__ float s_pts[NB][3];
    if (threadIdx.x < NB * 3) {
        s_pts[threadIdx.x / 3][threadIdx.x % 3] = points[n0 * 3 + threadIdx.x] * 0.25f;
    }
    __syncthreads();

    // ---- per-g state, loaded/derived once ----
    const float px = positions[g * 3 + 0];
    const float py = positions[g * 3 + 1];
    const float pz = positions[g * 3 + 2];

    const float isx = 1.0f / (scales[g * 3 + 0] + 1e-6f);
    const float isy = 1.0f / (scales[g * 3 + 1] + 1e-6f);
    const float isz = 1.0f / (scales[g * 3 + 2] + 1e-6f);

    const float q0 = rotations[g * 4 + 0];
    const float q1 = rotations[g * 4 + 1];
    const float q2 = rotations[g * 4 + 2];
    const float q3 = rotations[g * 4 + 3];

    // quaternion -> 3x3 (no normalization, same as reference)
    const float m00 = 1.0f - 2.0f * (q2 * q2 + q3 * q3);
    const float m01 = 2.0f * (q1 * q2 - q0 * q3);
    const float m02 = 2.0f * (q1 * q3 + q0 * q2);
    const float m10 = 2.0f * (q1 * q2 + q0 * q3);
    const float m11 = 1.0f - 2.0f * (q1 * q1 + q3 * q3);
    const float m12 = 2.0f * (q2 * q3 - q0 * q1);
    const float m20 = 2.0f * (q1 * q3 - q0 * q2);
    const float m21 = 2.0f * (q2 * q3 + q0 * q1);
    const float m22 = 1.0f - 2.0f * (q1 * q1 + q2 * q2);

    // SH basis constants folded into the per-g coefficients.
    const float c0  = 0.28209479177387814f;  // 0.5*sqrt(1/pi)
    const float c1  = 0.48860251190291992f;  // sqrt(3/(4pi))
    const float c2a = 0.54627421529603959f;  // 0.5*sqrt(15/(4pi))
    const float c2b = 0.15769578262626002f;  // 0.5*sqrt(5/(16pi))
    const float c2c = 0.27313710764801980f;  // 0.5*sqrt(15/(16pi))

    const float sh0 = sh[g * 9 + 0] * c0;
    const float sh1 = sh[g * 9 + 1] * c1;
    const float sh2 = sh[g * 9 + 2] * c1;
    const float sh3 = sh[g * 9 + 3] * c1;
    const float sh4 = sh[g * 9 + 4] * c2a;
    const float sh5 = sh[g * 9 + 5] * c2a;
    const float sh6 = sh[g * 9 + 6] * c2b;
    const float sh7 = sh[g * 9 + 7] * c2a;
    const float sh8 = sh[g * 9 + 8] * c2c;

    // sigma = softplus(opacity), written once (by the y==0 slice)
    if (blockIdx.y == 0) {
        const float o = opacity[g];
        out_sigma[g] = fmaxf(o, 0.0f) + log1pf(expf(-fabsf(o)));
    }

    // ---- n loop ----
    #pragma unroll 4
    for (int k = 0; k < NB; ++k) {
        const float dsx = (s_pts[k][0] - px) * isx;
        const float dsy = (s_pts[k][1] - py) * isy;
        const float dsz = (s_pts[k][2] - pz) * isz;

        const float rx = fmaf(m00, dsx, fmaf(m01, dsy, m02 * dsz));
        const float ry = fmaf(m10, dsx, fmaf(m11, dsy, m12 * dsz));
        const float rz = fmaf(m20, dsx, fmaf(m21, dsy, m22 * dsz));

        const float inv = rsqrtf(fmaf(rx, rx, fmaf(ry, ry, rz * rz)));
        const float x = rx * inv;
        const float y = ry * inv;
        const float z = rz * inv;

        float dot = sh0;
        dot = fmaf(sh1, y, dot);
        dot = fmaf(sh2, z, dot);
        dot = fmaf(sh3, x, dot);
        dot = fmaf(sh4, x * y, dot);
        dot = fmaf(sh5, y * z, dot);
        dot = fmaf(sh6, fmaf(3.0f, z * z, -1.0f), dot);
        dot = fmaf(sh7, x * z, dot);
        dot = fmaf(sh8, fmaf(x, x, -(y * y)), dot);

        const float rgb = 1.0f / (1.0f + expf(-dot));
        out_rgb[(n0 + k) * GRID_G + g] = rgb;
    }
}

extern "C" void kernel_launch(void* const* d_in, const int* in_sizes, int n_in,
                              void* d_out, int out_size, void* d_ws, size_t ws_size,
                              hipStream_t stream) {
    const float* points    = (const float*)d_in[0];  // [256,3]
    const float* positions = (const float*)d_in[1];  // [32,32,32,3]
    const float* scales    = (const float*)d_in[2];  // [32,32,32,3]
    const float* rotations = (const float*)d_in[3];  // [32,32,32,4]
    const float* opacity   = (const float*)d_in[4];  // [32,32,32,1]
    const float* sh_coeff  = (const float*)d_in[5];  // [32,32,32,9]

    float* out_rgb   = (float*)d_out;                       // [N, G]
    float* out_sigma = (float*)d_out + (size_t)NPTS * GRID_G; // [G]

    dim3 grid(GRID_G / BLK, NPTS / NB);  // (128, 8)
    dim3 block(BLK);
    gauss_splat_kernel<<<grid, block, 0, stream>>>(
        points, positions, scales, rotations, opacity, sh_coeff,
        out_rgb, out_sigma);
}